// Round 9
// baseline (2395.532 us; speedup 1.0000x reference)
//
#include <hip/hip_runtime.h>
#include <hip/hip_bf16.h>

// LSTM B=256 T=512 H=256 E=6 V=10 C=10. fp32 in/out.
// ROUND 9: 32 blocks x 512 threads, each block owns 8 batch cols (c0=bid*8).
// B-frag duplicates h into n=8..15 (col = l&7) -> lanes l>=8 hold acc identical
// to lanes l-8; elementwise assigns rt = l>>3 so EVERY thread does 4 elements
// (halved act issue per CU) with zero redistribution. MFMA per CU unchanged.
// INT8: weights per-row quantized, register-resident A-frags
// (mfma_i32_16x16x64_i8); h quantized at 127, double-buffered LDS, 1 barrier.
// Activations: exp2+rcp (LUTs were bank-conflict-bound, round 8).

typedef __attribute__((ext_vector_type(4))) int   int4v;
typedef __attribute__((ext_vector_type(8))) short short8;
typedef __attribute__((ext_vector_type(4))) short short4v;
typedef __attribute__((ext_vector_type(4))) float float4v;

#define MFMA_I8(a, b, c) __builtin_amdgcn_mfma_i32_16x16x64_i8(a, b, c, 0, 0, 0)

#define K_TANH (-2.8853900817779268f)   // exp2(K_TANH*x) = e^(-2x)
#define K_SIG  (-1.4426950408889634f)   // exp2(K_SIG*x)  = e^(-x)

__device__ __forceinline__ float b2f(short s) {
    union { unsigned int u; float f; } v; v.u = ((unsigned int)(unsigned short)s) << 16; return v.f;
}
__device__ __forceinline__ short f2b(float f) {
    __hip_bfloat16 b = __float2bfloat16(f); return *(short*)&b;
}
__device__ __forceinline__ float fexp2(float x) {
#if __has_builtin(__builtin_amdgcn_exp2f)
    return __builtin_amdgcn_exp2f(x);
#else
    return __expf(x * 0.6931471805599453f);
#endif
}
__device__ __forceinline__ float frcp(float x) { return __builtin_amdgcn_rcpf(x); }

__global__ __attribute__((amdgpu_flat_work_group_size(512, 512), amdgpu_waves_per_eu(2, 2)))
void lstm_i8(
    const int* __restrict__ x,
    const float* __restrict__ emb,
    const float* __restrict__ Wxg, const float* __restrict__ Whg, const float* __restrict__ bg,
    const float* __restrict__ Wxi, const float* __restrict__ Whi, const float* __restrict__ bi,
    const float* __restrict__ Wxf, const float* __restrict__ Whf, const float* __restrict__ bff,
    const float* __restrict__ Wxo, const float* __restrict__ Who, const float* __restrict__ bo,
    const float* __restrict__ Wp, const float* __restrict__ bp,
    float* __restrict__ out)
{
    const int tid = threadIdx.x, bid = blockIdx.x;
    const int c0 = bid * 8;                 // 8 batch columns per block
    const int w = tid >> 6, lane = tid & 63;
    const int l = lane & 15, q = lane >> 4;
    const int cl = l & 7;                   // this thread's column (dup lanes share)
    const int rt = l >> 3;                  // this thread's row-tile (0 or 1)
    const int rw = 32 * w;

    __shared__ __align__(16) unsigned int hbuf[2][8 * 272 / 4];  // h i8 [parity][col][k], stride 272B
    __shared__ __align__(16) short hfin[8 * 264];                // final h bf16 [col][k]
    __shared__ unsigned char xdig2[512 * 8];                     // [t][col]
    __shared__ __align__(16) short tblL[16 * 720];               // [w2rt][d][q][g*4+i] bf16 (kg-scaled)
    __shared__ float scaleL[4 * 256];                            // per-gate per-row max|W|

    const float* WxT[4] = {Wxg, Wxi, Wxf, Wxo};
    const float* WhT[4] = {Whg, Whi, Whf, Who};

    // ---- init: zero h buf0, stage digits ----
    for (int i = tid; i < 8 * 272 / 4; i += 512) hbuf[0][i] = 0u;
    for (int i = tid; i < 4096; i += 512)
        xdig2[i] = (unsigned char)x[(c0 + (i & 7)) * 512 + (i >> 3)];

    // ---- x-path table, gate-scale folded: tbl = kg * (Wx@emb)[row][d] ----
    for (int i = tid; i < 10240; i += 512) {
        int gi = i & 15, g = gi >> 2, io = gi & 3;
        int qq = (i >> 4) & 3;
        int d  = (i >> 6) % 10;
        int rtw = i / 640;                                   // w*2+rt
        int row = (rtw >> 1) * 32 + (rtw & 1) * 16 + qq * 4 + io;
        float s = 0.f;
        #pragma unroll
        for (int e = 0; e < 6; e++) s += WxT[g][row * 6 + e] * emb[d * 6 + e];
        tblL[rtw * 720 + d * 72 + qq * 16 + gi] = f2b(s * (g == 0 ? K_TANH : K_SIG));
    }

    // ---- weight quantization: per-row scale, i8 A-frags in registers ----
    // A[m=lane&15 -> row rw+16rt'+l][k = 64kt+16q+j], both rt' tiles per wave
    int4v wa[4][2][4];
    #pragma unroll
    for (int g = 0; g < 4; g++)
        #pragma unroll
        for (int rr = 0; rr < 2; rr++) {
            const float* Wr = WhT[g] + (rw + 16 * rr + l) * 256 + q * 16;
            float mx = 0.f;
            #pragma unroll
            for (int kt = 0; kt < 4; kt++)
                #pragma unroll
                for (int c4 = 0; c4 < 4; c4++) {
                    float4v v = *(const float4v*)(Wr + kt * 64 + c4 * 4);
                    #pragma unroll
                    for (int j = 0; j < 4; j++) mx = fmaxf(mx, fabsf(v[j]));
                }
            mx = fmaxf(mx, __shfl_xor(mx, 16));
            mx = fmaxf(mx, __shfl_xor(mx, 32));
            mx = fmaxf(mx, 1e-20f);
            if (q == 0) scaleL[g * 256 + rw + 16 * rr + l] = mx;
            float qs = 127.f / mx;
            #pragma unroll
            for (int kt = 0; kt < 4; kt++) {
                int4v f;
                #pragma unroll
                for (int dw = 0; dw < 4; dw++) {
                    float4v v = *(const float4v*)(Wr + kt * 64 + dw * 4);
                    int word = 0;
                    #pragma unroll
                    for (int byt = 0; byt < 4; byt++) {
                        int z = (int)rintf(v[byt] * qs);
                        word |= (z & 255) << (8 * byt);
                    }
                    f[dw] = word;
                }
                wa[g][rr][kt] = f;
            }
        }

    __syncthreads();   // scaleL/tblL/xdig2/hbuf[0] visible

    // ---- loop-invariant dequant scales (this thread's rows: rw+16rt+4q+i) ----
    float dscl[4][4];
    #pragma unroll
    for (int g = 0; g < 4; g++) {
        float kk = (g == 0 ? K_TANH : K_SIG) * (1.f / 16129.f);   // 127^2
        #pragma unroll
        for (int i = 0; i < 4; i++)
            dscl[g][i] = scaleL[g * 256 + rw + 16 * rt + 4 * q + i] * kk;
    }
    float bSc[4];
    bSc[0] = bg[c0 + cl] * K_TANH; bSc[1] = bi[c0 + cl] * K_SIG;
    bSc[2] = bff[c0 + cl] * K_SIG; bSc[3] = bo[c0 + cl] * K_SIG;

    float cs[4] = {0.f, 0.f, 0.f, 0.f};
    float hl[4];   // last-step h for projection

    for (int t = 0; t < 512; t++) {
        const int p = t & 1;
        const char* hbase = (const char*)hbuf[p] + cl * 272 + q * 16;   // dup lanes broadcast
        char*       hdst  = (char*)hbuf[1 - p]  + cl * 272 + rw + 16 * rt + 4 * q;

        int4v acc[4][2];
        #pragma unroll
        for (int g = 0; g < 4; g++)
            #pragma unroll
            for (int rr = 0; rr < 2; rr++)
                acc[g][rr] = (int4v){0, 0, 0, 0};

        int dg = xdig2[t * 8 + cl];
        const short* tp = &tblL[(w * 2 + rt) * 720 + dg * 72 + q * 16];
        short8 tva = *(const short8*)tp, tvb = *(const short8*)(tp + 8);

        #pragma unroll
        for (int kt = 0; kt < 4; kt++) {
            int4v hf = *(const int4v*)(hbase + kt * 64);   // B[k=64kt+16q+j][n: col l&7, dup]
            #pragma unroll
            for (int g = 0; g < 4; g++) {
                acc[g][0] = MFMA_I8(wa[g][0][kt], hf, acc[g][0]);
                acc[g][1] = MFMA_I8(wa[g][1][kt], hf, acc[g][1]);
            }
        }
        // no barrier: writes go to the other h buffer

        // ---- elementwise: thread owns rows rw+16rt+4q+i (i=0..3), col c0+cl ----
        {
            int word = 0;
            #pragma unroll
            for (int i = 0; i < 4; i++) {
                float pg = fmaf((float)acc[0][rt][i], dscl[0][i], b2f(tva[i])     + bSc[0]);
                float pi = fmaf((float)acc[1][rt][i], dscl[1][i], b2f(tva[4 + i]) + bSc[1]);
                float pf = fmaf((float)acc[2][rt][i], dscl[2][i], b2f(tvb[i])     + bSc[2]);
                float po = fmaf((float)acc[3][rt][i], dscl[3][i], b2f(tvb[4 + i]) + bSc[3]);
                float gg = fmaf(2.f, frcp(1.f + fexp2(pg)), -1.f);   // tanh
                float ii = frcp(1.f + fexp2(pi));
                float ff = frcp(1.f + fexp2(pf));
                float oo = frcp(1.f + fexp2(po));
                float c  = fmaf(gg, ii, cs[i] * ff);
                cs[i] = c;
                float th = fmaf(2.f, frcp(1.f + fexp2(K_TANH * c)), -1.f);
                float hh = th * oo;
                hl[i] = hh;
                int hq = (int)rintf(hh * 127.f);
                word |= (hq & 255) << (8 * i);
            }
            *(int*)hdst = word;
        }
        __syncthreads();   // h_t (other buffer) fully written; h_{t-1} reads all done
    }

    // ---- stage final h (exact f32->bf16) for projection ----
    {
        short4v hw;
        hw[0] = f2b(hl[0]); hw[1] = f2b(hl[1]);
        hw[2] = f2b(hl[2]); hw[3] = f2b(hl[3]);
        *(short4v*)&hfin[cl * 264 + rw + 16 * rt + 4 * q] = hw;
    }
    __syncthreads();

    // ---- projection: out[c0+col][cls] = Wp[cls] . h_final + bp[cls] ----
    if (tid < 80) {
        int col = tid / 10, cls = tid - col * 10;
        const short* hcol = &hfin[col * 264];
        const float* wrow = Wp + cls * 256;
        float s = 0.f;
        #pragma unroll 8
        for (int k = 0; k < 256; k++) s += b2f(hcol[k]) * wrow[k];
        out[(c0 + col) * 10 + cls] = s + bp[cls];
    }
}

extern "C" void kernel_launch(void* const* d_in, const int* in_sizes, int n_in,
                              void* d_out, int out_size, void* d_ws, size_t ws_size,
                              hipStream_t stream) {
    const int*   x   = (const int*)d_in[0];
    const float* emb = (const float*)d_in[1];
    const float* Wxg = (const float*)d_in[2];
    const float* Whg = (const float*)d_in[3];
    const float* bg  = (const float*)d_in[4];
    const float* Wxi = (const float*)d_in[5];
    const float* Whi = (const float*)d_in[6];
    const float* bi  = (const float*)d_in[7];
    const float* Wxf = (const float*)d_in[8];
    const float* Whf = (const float*)d_in[9];
    const float* bff = (const float*)d_in[10];
    const float* Wxo = (const float*)d_in[11];
    const float* Who = (const float*)d_in[12];
    const float* bo  = (const float*)d_in[13];
    const float* Wp  = (const float*)d_in[14];
    const float* bp  = (const float*)d_in[15];

    hipLaunchKernelGGL(lstm_i8, dim3(32), dim3(512), 0, stream,
                       x, emb, Wxg, Whg, bg, Wxi, Whi, bi, Wxf, Whf, bff,
                       Wxo, Who, bo, Wp, bp, (float*)d_out);
}

// Round 10
// 779.711 us; speedup vs baseline: 3.0723x; 3.0723x over previous
//
#include <hip/hip_runtime.h>
#include <hip/hip_bf16.h>

// LSTM B=256 T=512 H=256 E=6 V=10 C=10. fp32 in/out.
// ROUND 10: 32 blocks x 512 threads, each block owns 8 batch cols (c0=bid*8).
// B-frag duplicates h into n=8..15 (col = l&7) -> lanes l>=8 hold acc identical
// to lanes l-8; elementwise assigns rt = l>>3 so EVERY thread does 4 elements.
// FIX vs round 9: acc tile selection via explicit per-element ternaries
// (v_cndmask), NOT acc[g][rt][i] divergent register indexing (which lowered to
// scratch spill: r9 FETCH+WRITE grew ~12 MB and VALUBusy hit 90%).
// INT8: weights per-row quantized, register-resident A-frags
// (mfma_i32_16x16x64_i8); h quantized at 127, double-buffered LDS, 1 barrier.

typedef __attribute__((ext_vector_type(4))) int   int4v;
typedef __attribute__((ext_vector_type(8))) short short8;
typedef __attribute__((ext_vector_type(4))) short short4v;
typedef __attribute__((ext_vector_type(4))) float float4v;

#define MFMA_I8(a, b, c) __builtin_amdgcn_mfma_i32_16x16x64_i8(a, b, c, 0, 0, 0)

#define K_TANH (-2.8853900817779268f)   // exp2(K_TANH*x) = e^(-2x)
#define K_SIG  (-1.4426950408889634f)   // exp2(K_SIG*x)  = e^(-x)

__device__ __forceinline__ float b2f(short s) {
    union { unsigned int u; float f; } v; v.u = ((unsigned int)(unsigned short)s) << 16; return v.f;
}
__device__ __forceinline__ short f2b(float f) {
    __hip_bfloat16 b = __float2bfloat16(f); return *(short*)&b;
}
__device__ __forceinline__ float fexp2(float x) {
#if __has_builtin(__builtin_amdgcn_exp2f)
    return __builtin_amdgcn_exp2f(x);
#else
    return __expf(x * 0.6931471805599453f);
#endif
}
__device__ __forceinline__ float frcp(float x) { return __builtin_amdgcn_rcpf(x); }

__global__ __attribute__((amdgpu_flat_work_group_size(512, 512), amdgpu_waves_per_eu(2, 2)))
void lstm_i8(
    const int* __restrict__ x,
    const float* __restrict__ emb,
    const float* __restrict__ Wxg, const float* __restrict__ Whg, const float* __restrict__ bg,
    const float* __restrict__ Wxi, const float* __restrict__ Whi, const float* __restrict__ bi,
    const float* __restrict__ Wxf, const float* __restrict__ Whf, const float* __restrict__ bff,
    const float* __restrict__ Wxo, const float* __restrict__ Who, const float* __restrict__ bo,
    const float* __restrict__ Wp, const float* __restrict__ bp,
    float* __restrict__ out)
{
    const int tid = threadIdx.x, bid = blockIdx.x;
    const int c0 = bid * 8;                 // 8 batch columns per block
    const int w = tid >> 6, lane = tid & 63;
    const int l = lane & 15, q = lane >> 4;
    const int cl = l & 7;                   // this thread's column (dup lanes share)
    const int rt = l >> 3;                  // this thread's row-tile (0 or 1)
    const int rw = 32 * w;

    __shared__ __align__(16) unsigned int hbuf[2][8 * 272 / 4];  // h i8 [parity][col][k], stride 272B
    __shared__ __align__(16) short hfin[8 * 264];                // final h bf16 [col][k]
    __shared__ unsigned char xdig2[512 * 8];                     // [t][col]
    __shared__ __align__(16) short tblL[16 * 720];               // [w2rt][d][q][g*4+i] bf16 (kg-scaled)
    __shared__ float scaleL[4 * 256];                            // per-gate per-row max|W|

    const float* WxT[4] = {Wxg, Wxi, Wxf, Wxo};
    const float* WhT[4] = {Whg, Whi, Whf, Who};

    // ---- init: zero h buf0, stage digits ----
    for (int i = tid; i < 8 * 272 / 4; i += 512) hbuf[0][i] = 0u;
    for (int i = tid; i < 4096; i += 512)
        xdig2[i] = (unsigned char)x[(c0 + (i & 7)) * 512 + (i >> 3)];

    // ---- x-path table, gate-scale folded: tbl = kg * (Wx@emb)[row][d] ----
    for (int i = tid; i < 10240; i += 512) {
        int gi = i & 15, g = gi >> 2, io = gi & 3;
        int qq = (i >> 4) & 3;
        int d  = (i >> 6) % 10;
        int rtw = i / 640;                                   // w*2+rt
        int row = (rtw >> 1) * 32 + (rtw & 1) * 16 + qq * 4 + io;
        float s = 0.f;
        #pragma unroll
        for (int e = 0; e < 6; e++) s += WxT[g][row * 6 + e] * emb[d * 6 + e];
        tblL[rtw * 720 + d * 72 + qq * 16 + gi] = f2b(s * (g == 0 ? K_TANH : K_SIG));
    }

    // ---- weight quantization: per-row scale, i8 A-frags in registers ----
    // A[m=lane&15 -> row rw+16rr+l][k = 64kt+16q+j], both rr tiles per wave
    int4v wa[4][2][4];
    #pragma unroll
    for (int g = 0; g < 4; g++)
        #pragma unroll
        for (int rr = 0; rr < 2; rr++) {
            const float* Wr = WhT[g] + (rw + 16 * rr + l) * 256 + q * 16;
            float mx = 0.f;
            #pragma unroll
            for (int kt = 0; kt < 4; kt++)
                #pragma unroll
                for (int c4 = 0; c4 < 4; c4++) {
                    float4v v = *(const float4v*)(Wr + kt * 64 + c4 * 4);
                    #pragma unroll
                    for (int j = 0; j < 4; j++) mx = fmaxf(mx, fabsf(v[j]));
                }
            mx = fmaxf(mx, __shfl_xor(mx, 16));
            mx = fmaxf(mx, __shfl_xor(mx, 32));
            mx = fmaxf(mx, 1e-20f);
            if (q == 0) scaleL[g * 256 + rw + 16 * rr + l] = mx;
            float qs = 127.f / mx;
            #pragma unroll
            for (int kt = 0; kt < 4; kt++) {
                int4v f;
                #pragma unroll
                for (int dw = 0; dw < 4; dw++) {
                    float4v v = *(const float4v*)(Wr + kt * 64 + dw * 4);
                    int word = 0;
                    #pragma unroll
                    for (int byt = 0; byt < 4; byt++) {
                        int z = (int)rintf(v[byt] * qs);
                        word |= (z & 255) << (8 * byt);
                    }
                    f[dw] = word;
                }
                wa[g][rr][kt] = f;
            }
        }

    __syncthreads();   // scaleL/tblL/xdig2/hbuf[0] visible

    // ---- loop-invariant dequant scales (this thread's rows: rw+16rt+4q+i) ----
    float dscl[4][4];
    #pragma unroll
    for (int g = 0; g < 4; g++) {
        float kk = (g == 0 ? K_TANH : K_SIG) * (1.f / 16129.f);   // 127^2
        #pragma unroll
        for (int i = 0; i < 4; i++)
            dscl[g][i] = scaleL[g * 256 + rw + 16 * rt + 4 * q + i] * kk;
    }
    float bSc[4];
    bSc[0] = bg[c0 + cl] * K_TANH; bSc[1] = bi[c0 + cl] * K_SIG;
    bSc[2] = bff[c0 + cl] * K_SIG; bSc[3] = bo[c0 + cl] * K_SIG;

    float cs[4] = {0.f, 0.f, 0.f, 0.f};
    float hl[4];   // last-step h for projection
    const bool hi = (rt != 0);   // one v_cmp; reused by all cndmask selects

    for (int t = 0; t < 512; t++) {
        const int p = t & 1;
        const char* hbase = (const char*)hbuf[p] + cl * 272 + q * 16;   // dup lanes broadcast
        char*       hdst  = (char*)hbuf[1 - p]  + cl * 272 + rw + 16 * rt + 4 * q;

        int4v acc[4][2];
        #pragma unroll
        for (int g = 0; g < 4; g++)
            #pragma unroll
            for (int rr = 0; rr < 2; rr++)
                acc[g][rr] = (int4v){0, 0, 0, 0};

        int dg = xdig2[t * 8 + cl];
        const short* tp = &tblL[(w * 2 + rt) * 720 + dg * 72 + q * 16];
        short8 tva = *(const short8*)tp, tvb = *(const short8*)(tp + 8);

        #pragma unroll
        for (int kt = 0; kt < 4; kt++) {
            int4v hf = *(const int4v*)(hbase + kt * 64);   // B[k=64kt+16q+j][n: col l&7, dup]
            #pragma unroll
            for (int g = 0; g < 4; g++) {
                acc[g][0] = MFMA_I8(wa[g][0][kt], hf, acc[g][0]);
                acc[g][1] = MFMA_I8(wa[g][1][kt], hf, acc[g][1]);
            }
        }
        // no barrier: writes go to the other h buffer

        // ---- elementwise: thread owns rows rw+16rt+4q+i (i=0..3), col c0+cl ----
        // acc tile select via CONSTANT-index ternaries -> v_cndmask (no scratch!)
        {
            int word = 0;
            #pragma unroll
            for (int i = 0; i < 4; i++) {
                int a0 = hi ? acc[0][1][i] : acc[0][0][i];
                int a1 = hi ? acc[1][1][i] : acc[1][0][i];
                int a2 = hi ? acc[2][1][i] : acc[2][0][i];
                int a3 = hi ? acc[3][1][i] : acc[3][0][i];
                float pg = fmaf((float)a0, dscl[0][i], b2f(tva[i])     + bSc[0]);
                float pi = fmaf((float)a1, dscl[1][i], b2f(tva[4 + i]) + bSc[1]);
                float pf = fmaf((float)a2, dscl[2][i], b2f(tvb[i])     + bSc[2]);
                float po = fmaf((float)a3, dscl[3][i], b2f(tvb[4 + i]) + bSc[3]);
                float gg = fmaf(2.f, frcp(1.f + fexp2(pg)), -1.f);   // tanh
                float ii = frcp(1.f + fexp2(pi));
                float ff = frcp(1.f + fexp2(pf));
                float oo = frcp(1.f + fexp2(po));
                float c  = fmaf(gg, ii, cs[i] * ff);
                cs[i] = c;
                float th = fmaf(2.f, frcp(1.f + fexp2(K_TANH * c)), -1.f);
                float hh = th * oo;
                hl[i] = hh;
                int hq = (int)rintf(hh * 127.f);
                word |= (hq & 255) << (8 * i);
            }
            *(int*)hdst = word;
        }
        __syncthreads();   // h_t (other buffer) fully written; h_{t-1} reads all done
    }

    // ---- stage final h (exact f32->bf16) for projection ----
    {
        short4v hw;
        hw[0] = f2b(hl[0]); hw[1] = f2b(hl[1]);
        hw[2] = f2b(hl[2]); hw[3] = f2b(hl[3]);
        *(short4v*)&hfin[cl * 264 + rw + 16 * rt + 4 * q] = hw;
    }
    __syncthreads();

    // ---- projection: out[c0+col][cls] = Wp[cls] . h_final + bp[cls] ----
    if (tid < 80) {
        int col = tid / 10, cls = tid - col * 10;
        const short* hcol = &hfin[col * 264];
        const float* wrow = Wp + cls * 256;
        float s = 0.f;
        #pragma unroll 8
        for (int k = 0; k < 256; k++) s += b2f(hcol[k]) * wrow[k];
        out[(c0 + col) * 10 + cls] = s + bp[cls];
    }
}

extern "C" void kernel_launch(void* const* d_in, const int* in_sizes, int n_in,
                              void* d_out, int out_size, void* d_ws, size_t ws_size,
                              hipStream_t stream) {
    const int*   x   = (const int*)d_in[0];
    const float* emb = (const float*)d_in[1];
    const float* Wxg = (const float*)d_in[2];
    const float* Whg = (const float*)d_in[3];
    const float* bg  = (const float*)d_in[4];
    const float* Wxi = (const float*)d_in[5];
    const float* Whi = (const float*)d_in[6];
    const float* bi  = (const float*)d_in[7];
    const float* Wxf = (const float*)d_in[8];
    const float* Whf = (const float*)d_in[9];
    const float* bff = (const float*)d_in[10];
    const float* Wxo = (const float*)d_in[11];
    const float* Who = (const float*)d_in[12];
    const float* bo  = (const float*)d_in[13];
    const float* Wp  = (const float*)d_in[14];
    const float* bp  = (const float*)d_in[15];

    hipLaunchKernelGGL(lstm_i8, dim3(32), dim3(512), 0, stream,
                       x, emb, Wxg, Whg, bg, Wxi, Whi, bi, Wxf, Whf, bff,
                       Wxo, Who, bo, Wp, bp, (float*)d_out);
}

// Round 11
// 610.969 us; speedup vs baseline: 3.9209x; 1.2762x over previous
//
#include <hip/hip_runtime.h>
#include <hip/hip_bf16.h>

// LSTM B=256 T=512 H=256 E=6 V=10 C=10. fp32 in/out.
// ROUND 11: 128 blocks x 512 threads, each block owns 2 batch cols (c0=bid*2).
// B-frag duplicates h 8x into n-slots (col = l&1); group bits g3 = (l>>1)&7
// select (rr = g3>>2, i = g3&3) -> EVERY thread activates exactly 1 element.
// acc tile selection: 7 constant-index cndmasks per gate (r10-verified pattern;
// NEVER divergent-index a register array - r9 lowered that to scratch).
// INT8: weights per-row quantized, register-resident A-frags
// (mfma_i32_16x16x64_i8, exact i32 accum); h quantized at 127, double-buffered
// LDS, 1 barrier/step. x-path table: f32 [row][digit][4 gates] (+pad),
// one ds_read_b128 per element.

typedef __attribute__((ext_vector_type(4))) int   int4v;
typedef __attribute__((ext_vector_type(4))) float float4v;

#define MFMA_I8(a, b, c) __builtin_amdgcn_mfma_i32_16x16x64_i8(a, b, c, 0, 0, 0)

#define K_TANH (-2.8853900817779268f)   // exp2(K_TANH*x) = e^(-2x)
#define K_SIG  (-1.4426950408889634f)   // exp2(K_SIG*x)  = e^(-x)

__device__ __forceinline__ short f2b(float f) {
    __hip_bfloat16 b = __float2bfloat16(f); return *(short*)&b;
}
__device__ __forceinline__ float b2f(short s) {
    union { unsigned int u; float f; } v; v.u = ((unsigned int)(unsigned short)s) << 16; return v.f;
}
__device__ __forceinline__ float fexp2(float x) {
#if __has_builtin(__builtin_amdgcn_exp2f)
    return __builtin_amdgcn_exp2f(x);
#else
    return __expf(x * 0.6931471805599453f);
#endif
}
__device__ __forceinline__ float frcp(float x) { return __builtin_amdgcn_rcpf(x); }

__global__ __attribute__((amdgpu_flat_work_group_size(512, 512), amdgpu_waves_per_eu(2, 2)))
void lstm_i8(
    const int* __restrict__ x,
    const float* __restrict__ emb,
    const float* __restrict__ Wxg, const float* __restrict__ Whg, const float* __restrict__ bg,
    const float* __restrict__ Wxi, const float* __restrict__ Whi, const float* __restrict__ bi,
    const float* __restrict__ Wxf, const float* __restrict__ Whf, const float* __restrict__ bff,
    const float* __restrict__ Wxo, const float* __restrict__ Who, const float* __restrict__ bo,
    const float* __restrict__ Wp, const float* __restrict__ bp,
    float* __restrict__ out)
{
    const int tid = threadIdx.x, bid = blockIdx.x;
    const int c0 = bid * 2;                 // 2 batch columns per block
    const int w = tid >> 6, lane = tid & 63;
    const int l = lane & 15, q = lane >> 4;
    const int col = l & 1;                  // this thread's column (8x dup)
    const int g3  = (l >> 1) & 7;           // selects (rr, i)
    const int si  = g3 & 3;                 // acc reg index
    const int srr = g3 >> 2;                // row tile
    const int rw  = 32 * w;
    const int row = rw + 16 * srr + 4 * q + si;   // this thread's hidden row

    __shared__ __align__(16) unsigned int hbuf[2][2 * 272 / 4];  // h i8 [parity][col][k], stride 272B
    __shared__ __align__(16) short hfin[2 * 264];                // final h bf16 [col][k]
    __shared__ unsigned char xdig2[512 * 2];                     // [t][col]
    __shared__ __align__(16) float tblf[256 * 44];               // [row][d][4 gates] f32, stride 44 dw
    __shared__ float scaleL[4 * 256];                            // per-gate per-row max|W|

    const float* WxT[4] = {Wxg, Wxi, Wxf, Wxo};
    const float* WhT[4] = {Whg, Whi, Whf, Who};

    // ---- init: zero h buf0, stage digits ----
    if (tid < 2 * 272 / 4) hbuf[0][tid] = 0u;
    for (int i = tid; i < 1024; i += 512)
        xdig2[i] = (unsigned char)x[(c0 + (i & 1)) * 512 + (i >> 1)];

    // ---- x-path table, gate-scale folded: tblf[row][d] = {kg*(Wx@emb)} ----
    for (int i = tid; i < 2560; i += 512) {
        int r = i / 10, d = i - r * 10;
        float4v v;
        #pragma unroll
        for (int g = 0; g < 4; g++) {
            float s = 0.f;
            #pragma unroll
            for (int e = 0; e < 6; e++) s += WxT[g][r * 6 + e] * emb[d * 6 + e];
            v[g] = s * (g == 0 ? K_TANH : K_SIG);
        }
        *(float4v*)&tblf[r * 44 + d * 4] = v;
    }

    // ---- weight quantization: per-row scale, i8 A-frags in registers ----
    // A[m=lane&15 -> row rw+16rr+l][k = 64kt+16q+j], both rr tiles per wave
    int4v wa[4][2][4];
    #pragma unroll
    for (int g = 0; g < 4; g++)
        #pragma unroll
        for (int rr = 0; rr < 2; rr++) {
            const float* Wr = WhT[g] + (rw + 16 * rr + l) * 256 + q * 16;
            float mx = 0.f;
            #pragma unroll
            for (int kt = 0; kt < 4; kt++)
                #pragma unroll
                for (int c4 = 0; c4 < 4; c4++) {
                    float4v v = *(const float4v*)(Wr + kt * 64 + c4 * 4);
                    #pragma unroll
                    for (int j = 0; j < 4; j++) mx = fmaxf(mx, fabsf(v[j]));
                }
            mx = fmaxf(mx, __shfl_xor(mx, 16));
            mx = fmaxf(mx, __shfl_xor(mx, 32));
            mx = fmaxf(mx, 1e-20f);
            if (q == 0) scaleL[g * 256 + rw + 16 * rr + l] = mx;
            float qs = 127.f / mx;
            #pragma unroll
            for (int kt = 0; kt < 4; kt++) {
                int4v f;
                #pragma unroll
                for (int dw = 0; dw < 4; dw++) {
                    float4v v = *(const float4v*)(Wr + kt * 64 + dw * 4);
                    int word = 0;
                    #pragma unroll
                    for (int byt = 0; byt < 4; byt++) {
                        int z = (int)rintf(v[byt] * qs);
                        word |= (z & 255) << (8 * byt);
                    }
                    f[dw] = word;
                }
                wa[g][rr][kt] = f;
            }
        }

    __syncthreads();   // scaleL/tblf/xdig2/hbuf[0] visible

    // ---- loop-invariant: dequant scales (this thread's row), biases (this col) ----
    float dscl[4];
    #pragma unroll
    for (int g = 0; g < 4; g++) {
        float kk = (g == 0 ? K_TANH : K_SIG) * (1.f / 16129.f);   // 127^2
        dscl[g] = scaleL[g * 256 + row] * kk;
    }
    float bSc[4];
    bSc[0] = bg[c0 + col] * K_TANH; bSc[1] = bi[c0 + col] * K_SIG;
    bSc[2] = bff[c0 + col] * K_SIG; bSc[3] = bo[c0 + col] * K_SIG;

    const bool bi1 = (si & 1) != 0;
    const bool bi2 = (si & 2) != 0;
    const bool brr = (srr != 0);
    const float* tprow = &tblf[row * 44];

    float cs = 0.f, hl = 0.f;

    for (int t = 0; t < 512; t++) {
        const int p = t & 1;
        const char* hbase = (const char*)hbuf[p] + col * 272 + q * 16;   // dup lanes broadcast

        int4v acc[4][2];
        #pragma unroll
        for (int g = 0; g < 4; g++)
            #pragma unroll
            for (int rr = 0; rr < 2; rr++)
                acc[g][rr] = (int4v){0, 0, 0, 0};

        int dg = xdig2[t * 2 + col];
        float4v tb = *(const float4v*)(tprow + dg * 4);   // {tg,ti,tf,to} kg-scaled

        #pragma unroll
        for (int kt = 0; kt < 4; kt++) {
            int4v hf = *(const int4v*)(hbase + kt * 64);   // B[k=64kt+16q+j][n: col l&1, dup]
            #pragma unroll
            for (int g = 0; g < 4; g++) {
                acc[g][0] = MFMA_I8(wa[g][0][kt], hf, acc[g][0]);
                acc[g][1] = MFMA_I8(wa[g][1][kt], hf, acc[g][1]);
            }
        }
        // no barrier: writes go to the other h buffer

        // ---- elementwise: ONE element (row, col) per thread ----
        // select acc[g][srr][si] via constant-index cndmask tree (7 per gate)
        int av[4];
        #pragma unroll
        for (int g = 0; g < 4; g++) {
            int s00 = bi1 ? acc[g][0][1] : acc[g][0][0];
            int s01 = bi1 ? acc[g][0][3] : acc[g][0][2];
            int s10 = bi1 ? acc[g][1][1] : acc[g][1][0];
            int s11 = bi1 ? acc[g][1][3] : acc[g][1][2];
            int s0  = bi2 ? s01 : s00;
            int s1  = bi2 ? s11 : s10;
            av[g]   = brr ? s1 : s0;
        }
        {
            float pg = fmaf((float)av[0], dscl[0], tb[0] + bSc[0]);
            float pi = fmaf((float)av[1], dscl[1], tb[1] + bSc[1]);
            float pf = fmaf((float)av[2], dscl[2], tb[2] + bSc[2]);
            float po = fmaf((float)av[3], dscl[3], tb[3] + bSc[3]);
            float gg = fmaf(2.f, frcp(1.f + fexp2(pg)), -1.f);   // tanh
            float ii = frcp(1.f + fexp2(pi));
            float ff = frcp(1.f + fexp2(pf));
            float oo = frcp(1.f + fexp2(po));
            float c  = fmaf(gg, ii, cs * ff);
            cs = c;
            float th = fmaf(2.f, frcp(1.f + fexp2(K_TANH * c)), -1.f);
            float hh = th * oo;
            hl = hh;
            int hq = (int)rintf(hh * 127.f);
            *((char*)hbuf[1 - p] + col * 272 + row) = (char)hq;
        }
        __syncthreads();   // h_t (other buffer) fully written; h_{t-1} reads all done
    }

    // ---- stage final h (exact f32->bf16) for projection ----
    hfin[col * 264 + row] = f2b(hl);
    __syncthreads();

    // ---- projection: out[c0+col][cls] = Wp[cls] . h_final + bp[cls] ----
    if (tid < 20) {
        int pc = tid / 10, cls = tid - pc * 10;
        const short* hcol = &hfin[pc * 264];
        const float* wrow = Wp + cls * 256;
        float s = 0.f;
        #pragma unroll 8
        for (int k = 0; k < 256; k++) s += b2f(hcol[k]) * wrow[k];
        out[(c0 + pc) * 10 + cls] = s + bp[cls];
    }
}

extern "C" void kernel_launch(void* const* d_in, const int* in_sizes, int n_in,
                              void* d_out, int out_size, void* d_ws, size_t ws_size,
                              hipStream_t stream) {
    const int*   x   = (const int*)d_in[0];
    const float* emb = (const float*)d_in[1];
    const float* Wxg = (const float*)d_in[2];
    const float* Whg = (const float*)d_in[3];
    const float* bg  = (const float*)d_in[4];
    const float* Wxi = (const float*)d_in[5];
    const float* Whi = (const float*)d_in[6];
    const float* bi  = (const float*)d_in[7];
    const float* Wxf = (const float*)d_in[8];
    const float* Whf = (const float*)d_in[9];
    const float* bff = (const float*)d_in[10];
    const float* Wxo = (const float*)d_in[11];
    const float* Who = (const float*)d_in[12];
    const float* bo  = (const float*)d_in[13];
    const float* Wp  = (const float*)d_in[14];
    const float* bp  = (const float*)d_in[15];

    hipLaunchKernelGGL(lstm_i8, dim3(128), dim3(512), 0, stream,
                       x, emb, Wxg, Whg, bg, Wxi, Whi, bi, Wxf, Whf, bff,
                       Wxo, Who, bo, Wp, bp, (float*)d_out);
}